// Round 1
// baseline (371.582 us; speedup 1.0000x reference)
//
#include <hip/hip_runtime.h>

#define D 128
#define SCAN_T 1024

// ---------------- histogram of row indices ----------------
__global__ __launch_bounds__(256) void hist_kernel(const int* __restrict__ row,
                                                   int* __restrict__ hist, int e) {
    int i = blockIdx.x * blockDim.x + threadIdx.x;
    if (i < e) atomicAdd(&hist[row[i]], 1);
}

// ---------------- single-block chunked exclusive scan ----------------
__global__ __launch_bounds__(SCAN_T) void scan_kernel(const int* __restrict__ hist,
                                                      int* __restrict__ offsets,
                                                      int* __restrict__ cursor,
                                                      float* __restrict__ rdeg, int n) {
    __shared__ int psum[SCAN_T];
    int t = threadIdx.x;
    int chunk = (n + SCAN_T - 1) / SCAN_T;
    int s0 = t * chunk;
    int s1 = min(s0 + chunk, n);
    int sum = 0;
    for (int i = s0; i < s1; ++i) sum += hist[i];
    psum[t] = sum;
    __syncthreads();
    // Hillis-Steele inclusive scan over 1024 partials
    for (int off = 1; off < SCAN_T; off <<= 1) {
        int add = (t >= off) ? psum[t - off] : 0;
        __syncthreads();
        psum[t] += add;
        __syncthreads();
    }
    int base = (t == 0) ? 0 : psum[t - 1];
    for (int i = s0; i < s1; ++i) {
        int v = hist[i];
        offsets[i] = base;
        cursor[i]  = base;
        rdeg[i]    = 1.0f / fmaxf((float)v, 1.0f);
        base += v;
    }
}

// ---------------- fill CSR col list via atomic cursors ----------------
__global__ __launch_bounds__(256) void fill_kernel(const int* __restrict__ ei, int e,
                                                   int* __restrict__ cursor,
                                                   int* __restrict__ csr) {
    int i = blockIdx.x * blockDim.x + threadIdx.x;
    if (i < e) {
        int r = ei[i];
        int c = ei[e + i];
        int pos = atomicAdd(&cursor[r], 1);
        csr[pos] = c;
    }
}

// ---------------- transpose both weight matrices (W[j][k] -> WT[k][j]) ----------------
__global__ __launch_bounds__(256) void transpose2_kernel(const float* __restrict__ W1,
                                                         float* __restrict__ WT1,
                                                         const float* __restrict__ W2,
                                                         float* __restrict__ WT2) {
    const float* src = blockIdx.x ? W2 : W1;
    float* dst       = blockIdx.x ? WT2 : WT1;
    for (int i = threadIdx.x; i < D * D; i += 256) {
        int j = i >> 7, k = i & 127;
        dst[k * D + j] = src[i];
    }
}

// ---------------- gather + mean-normalize: agg[n] = rdeg[n] * sum_{c in nbr(n)} src[c] ----------------
__global__ __launch_bounds__(256) void gather_kernel(const float* __restrict__ src,
                                                     const int* __restrict__ offsets,
                                                     const int* __restrict__ hist,
                                                     const int* __restrict__ csr,
                                                     const float* __restrict__ rdeg,
                                                     float* __restrict__ agg, int n) {
    int wid  = (blockIdx.x * blockDim.x + threadIdx.x) >> 6;
    int lane = threadIdx.x & 63;
    if (wid >= n) return;
    int start = offsets[wid];
    int cnt   = hist[wid];
    float2 acc = make_float2(0.f, 0.f);
    int i = 0;
    // 2-deep manual pipeline for load latency
    for (; i + 2 <= cnt; i += 2) {
        int c0 = csr[start + i];
        int c1 = csr[start + i + 1];
        float2 v0 = *(const float2*)&src[(size_t)c0 * D + lane * 2];
        float2 v1 = *(const float2*)&src[(size_t)c1 * D + lane * 2];
        acc.x += v0.x + v1.x;
        acc.y += v0.y + v1.y;
    }
    if (i < cnt) {
        int c0 = csr[start + i];
        float2 v0 = *(const float2*)&src[(size_t)c0 * D + lane * 2];
        acc.x += v0.x;
        acc.y += v0.y;
    }
    float r = rdeg[wid];
    float2 res = make_float2(acc.x * r, acc.y * r);
    *(float2*)&agg[(size_t)wid * D + lane * 2] = res;
}

// ---------------- out[r][j] = relu(bias[j] + sum_k A[r][k] * WT[k][j]) ----------------
#define TILE_R 64
__global__ __launch_bounds__(256) void linear_kernel(const float* __restrict__ A,
                                                     const float* __restrict__ WT,
                                                     const float* __restrict__ bias,
                                                     float* __restrict__ out, int n) {
    __shared__ float As[TILE_R][132];
    int t     = threadIdx.x;
    int rbase = blockIdx.x * TILE_R;
    int rows  = min(TILE_R, n - rbase);

    // stage A tile (rows x 128) into LDS, float4 coalesced
    for (int i = t; i < rows * 32; i += 256) {
        int r = i >> 5, q = i & 31;
        float4 v = *(const float4*)&A[(size_t)(rbase + r) * D + q * 4];
        *(float4*)&As[r][q * 4] = v;
    }
    __syncthreads();

    int jq = t & 31;          // output col group: j = jq*4 .. jq*4+3
    int r0 = (t >> 5) * 8;    // 8 rows per thread

    float4 acc[8];
#pragma unroll
    for (int r = 0; r < 8; ++r) acc[r] = make_float4(0.f, 0.f, 0.f, 0.f);

    const float4* WT4 = (const float4*)WT;
#pragma unroll 4
    for (int k = 0; k < D; k += 2) {
        float4 w0 = WT4[k * 32 + jq];
        float4 w1 = WT4[(k + 1) * 32 + jq];
#pragma unroll
        for (int r = 0; r < 8; ++r) {
            float2 a2 = *(const float2*)&As[r0 + r][k];
            acc[r].x += a2.x * w0.x; acc[r].y += a2.x * w0.y;
            acc[r].z += a2.x * w0.z; acc[r].w += a2.x * w0.w;
            acc[r].x += a2.y * w1.x; acc[r].y += a2.y * w1.y;
            acc[r].z += a2.y * w1.z; acc[r].w += a2.y * w1.w;
        }
    }

    float4 bv = ((const float4*)bias)[jq];
#pragma unroll
    for (int r = 0; r < 8; ++r) {
        int row = rbase + r0 + r;
        if (row < n) {
            float4 o;
            o.x = fmaxf(acc[r].x + bv.x, 0.f);
            o.y = fmaxf(acc[r].y + bv.y, 0.f);
            o.z = fmaxf(acc[r].z + bv.z, 0.f);
            o.w = fmaxf(acc[r].w + bv.w, 0.f);
            *(float4*)&out[(size_t)row * D + jq * 4] = o;
        }
    }
}

extern "C" void kernel_launch(void* const* d_in, const int* in_sizes, int n_in,
                              void* d_out, int out_size, void* d_ws, size_t ws_size,
                              hipStream_t stream) {
    const float* x  = (const float*)d_in[0];
    const int*   ei = (const int*)d_in[1];
    const float* W1 = (const float*)d_in[2];
    const float* b1 = (const float*)d_in[3];
    const float* W2 = (const float*)d_in[4];
    const float* b2 = (const float*)d_in[5];
    float* out = (float*)d_out;

    int N = in_sizes[0] / D;   // 50000
    int E = in_sizes[1] / 2;   // 600000

    // workspace carve (all offsets stay 16B-aligned: N and E are multiples of 4)
    int* hist    = (int*)d_ws;
    int* offsets = hist + N;
    int* cursor  = offsets + N;
    int* csr     = cursor + N;
    float* rdeg  = (float*)(csr + E);
    float* WT1   = rdeg + N;
    float* WT2   = WT1 + D * D;
    float* agg   = WT2 + D * D;

    hipMemsetAsync(hist, 0, (size_t)N * sizeof(int), stream);
    hist_kernel<<<(E + 255) / 256, 256, 0, stream>>>(ei, hist, E);
    scan_kernel<<<1, SCAN_T, 0, stream>>>(hist, offsets, cursor, rdeg, N);
    fill_kernel<<<(E + 255) / 256, 256, 0, stream>>>(ei, E, cursor, csr);
    transpose2_kernel<<<2, 256, 0, stream>>>(W1, WT1, W2, WT2);

    // round 1
    gather_kernel<<<(N + 3) / 4, 256, 0, stream>>>(x, offsets, hist, csr, rdeg, agg, N);
    linear_kernel<<<(N + TILE_R - 1) / TILE_R, 256, 0, stream>>>(agg, WT1, b1, out, N);
    // round 2 (reads h from d_out, then overwrites d_out)
    gather_kernel<<<(N + 3) / 4, 256, 0, stream>>>(out, offsets, hist, csr, rdeg, agg, N);
    linear_kernel<<<(N + TILE_R - 1) / TILE_R, 256, 0, stream>>>(agg, WT2, b2, out, N);
}

// Round 2
// 249.265 us; speedup vs baseline: 1.4907x; 1.4907x over previous
//
#include <hip/hip_runtime.h>

#define D 128

// ---------------- histogram of row indices ----------------
__global__ __launch_bounds__(256) void hist_kernel(const int* __restrict__ row,
                                                   int* __restrict__ hist, int e) {
    int i = blockIdx.x * blockDim.x + threadIdx.x;
    if (i < e) atomicAdd(&hist[row[i]], 1);
}

// ---------------- phase A: per-block partial sums ----------------
__global__ __launch_bounds__(256) void partial_kernel(const int* __restrict__ hist,
                                                      int* __restrict__ bsum, int n) {
    int i = blockIdx.x * 256 + threadIdx.x;
    int v = (i < n) ? hist[i] : 0;
#pragma unroll
    for (int off = 1; off < 64; off <<= 1) v += __shfl_xor(v, off);
    __shared__ int ws[4];
    int lane = threadIdx.x & 63, w = threadIdx.x >> 6;
    if (lane == 0) ws[w] = v;
    __syncthreads();
    if (threadIdx.x == 0) bsum[blockIdx.x] = ws[0] + ws[1] + ws[2] + ws[3];
}

// ---------------- phase B: exclusive scan of block sums (1 block, nb<=256) ----------------
__global__ __launch_bounds__(256) void bscan_kernel(int* __restrict__ bsum, int nb) {
    int t = threadIdx.x;
    int v = (t < nb) ? bsum[t] : 0;
    int lane = t & 63, w = t >> 6;
    int iv = v;
#pragma unroll
    for (int off = 1; off < 64; off <<= 1) {
        int n2 = __shfl_up(iv, off);
        if (lane >= off) iv += n2;
    }
    __shared__ int wt[4];
    if (lane == 63) wt[w] = iv;
    __syncthreads();
    int add = 0;
    for (int k = 0; k < w; ++k) add += wt[k];
    if (t < nb) bsum[t] = iv + add - v;   // exclusive
}

// ---------------- phase C: per-block exclusive scan + base; emit offsets/cursor/rdeg ----------------
__global__ __launch_bounds__(256) void finalize_kernel(const int* __restrict__ hist,
                                                       const int* __restrict__ bbase,
                                                       int* __restrict__ offsets,
                                                       int* __restrict__ cursor,
                                                       float* __restrict__ rdeg, int n) {
    int i = blockIdx.x * 256 + threadIdx.x;
    int v = (i < n) ? hist[i] : 0;
    int lane = threadIdx.x & 63, w = threadIdx.x >> 6;
    int iv = v;
#pragma unroll
    for (int off = 1; off < 64; off <<= 1) {
        int n2 = __shfl_up(iv, off);
        if (lane >= off) iv += n2;
    }
    __shared__ int wt[4];
    if (lane == 63) wt[w] = iv;
    __syncthreads();
    int add = bbase[blockIdx.x];
    for (int k = 0; k < w; ++k) add += wt[k];
    int excl = iv - v + add;
    if (i < n) {
        offsets[i] = excl;
        cursor[i]  = excl;
        rdeg[i]    = 1.0f / fmaxf((float)v, 1.0f);
    }
}

// ---------------- fill CSR col list via atomic cursors ----------------
__global__ __launch_bounds__(256) void fill_kernel(const int* __restrict__ ei, int e,
                                                   int* __restrict__ cursor,
                                                   int* __restrict__ csr) {
    int i = blockIdx.x * blockDim.x + threadIdx.x;
    if (i < e) {
        int r = ei[i];
        int c = ei[e + i];
        int pos = atomicAdd(&cursor[r], 1);
        csr[pos] = c;
    }
}

// ---------------- transpose both weight matrices (W[j][k] -> WT[k][j]) ----------------
__global__ __launch_bounds__(256) void transpose2_kernel(const float* __restrict__ W1,
                                                         float* __restrict__ WT1,
                                                         const float* __restrict__ W2,
                                                         float* __restrict__ WT2) {
    const float* src = blockIdx.x ? W2 : W1;
    float* dst       = blockIdx.x ? WT2 : WT1;
    for (int i = threadIdx.x; i < D * D; i += 256) {
        int j = i >> 7, k = i & 127;
        dst[k * D + j] = src[i];
    }
}

// ---------------- gather + mean-normalize: agg[n] = rdeg[n] * sum_{c in nbr(n)} src[c] ----------------
__global__ __launch_bounds__(256) void gather_kernel(const float* __restrict__ src,
                                                     const int* __restrict__ offsets,
                                                     const int* __restrict__ hist,
                                                     const int* __restrict__ csr,
                                                     const float* __restrict__ rdeg,
                                                     float* __restrict__ agg, int n) {
    int wid  = (blockIdx.x * blockDim.x + threadIdx.x) >> 6;
    int lane = threadIdx.x & 63;
    if (wid >= n) return;
    int start = offsets[wid];
    int cnt   = hist[wid];
    float2 acc = make_float2(0.f, 0.f);
    int i = 0;
    for (; i + 2 <= cnt; i += 2) {
        int c0 = csr[start + i];
        int c1 = csr[start + i + 1];
        float2 v0 = *(const float2*)&src[(size_t)c0 * D + lane * 2];
        float2 v1 = *(const float2*)&src[(size_t)c1 * D + lane * 2];
        acc.x += v0.x + v1.x;
        acc.y += v0.y + v1.y;
    }
    if (i < cnt) {
        int c0 = csr[start + i];
        float2 v0 = *(const float2*)&src[(size_t)c0 * D + lane * 2];
        acc.x += v0.x;
        acc.y += v0.y;
    }
    float r = rdeg[wid];
    float2 res = make_float2(acc.x * r, acc.y * r);
    *(float2*)&agg[(size_t)wid * D + lane * 2] = res;
}

// ---------------- out[r][j] = relu(bias[j] + sum_k A[r][k] * WT[k][j]) ----------------
#define TILE_R 64
__global__ __launch_bounds__(256) void linear_kernel(const float* __restrict__ A,
                                                     const float* __restrict__ WT,
                                                     const float* __restrict__ bias,
                                                     float* __restrict__ out, int n) {
    __shared__ float As[TILE_R][132];
    int t     = threadIdx.x;
    int rbase = blockIdx.x * TILE_R;
    int rows  = min(TILE_R, n - rbase);

    for (int i = t; i < rows * 32; i += 256) {
        int r = i >> 5, q = i & 31;
        float4 v = *(const float4*)&A[(size_t)(rbase + r) * D + q * 4];
        *(float4*)&As[r][q * 4] = v;
    }
    __syncthreads();

    int jq = t & 31;          // output col group: j = jq*4 .. jq*4+3
    int r0 = (t >> 5) * 8;    // 8 rows per thread

    float4 acc[8];
#pragma unroll
    for (int r = 0; r < 8; ++r) acc[r] = make_float4(0.f, 0.f, 0.f, 0.f);

    const float4* WT4 = (const float4*)WT;
#pragma unroll 4
    for (int k = 0; k < D; k += 2) {
        float4 w0 = WT4[k * 32 + jq];
        float4 w1 = WT4[(k + 1) * 32 + jq];
#pragma unroll
        for (int r = 0; r < 8; ++r) {
            float2 a2 = *(const float2*)&As[r0 + r][k];
            acc[r].x += a2.x * w0.x; acc[r].y += a2.x * w0.y;
            acc[r].z += a2.x * w0.z; acc[r].w += a2.x * w0.w;
            acc[r].x += a2.y * w1.x; acc[r].y += a2.y * w1.y;
            acc[r].z += a2.y * w1.z; acc[r].w += a2.y * w1.w;
        }
    }

    float4 bv = ((const float4*)bias)[jq];
#pragma unroll
    for (int r = 0; r < 8; ++r) {
        int row = rbase + r0 + r;
        if (row < n) {
            float4 o;
            o.x = fmaxf(acc[r].x + bv.x, 0.f);
            o.y = fmaxf(acc[r].y + bv.y, 0.f);
            o.z = fmaxf(acc[r].z + bv.z, 0.f);
            o.w = fmaxf(acc[r].w + bv.w, 0.f);
            *(float4*)&out[(size_t)row * D + jq * 4] = o;
        }
    }
}

extern "C" void kernel_launch(void* const* d_in, const int* in_sizes, int n_in,
                              void* d_out, int out_size, void* d_ws, size_t ws_size,
                              hipStream_t stream) {
    const float* x  = (const float*)d_in[0];
    const int*   ei = (const int*)d_in[1];
    const float* W1 = (const float*)d_in[2];
    const float* b1 = (const float*)d_in[3];
    const float* W2 = (const float*)d_in[4];
    const float* b2 = (const float*)d_in[5];
    float* out = (float*)d_out;

    int N = in_sizes[0] / D;   // 50000
    int E = in_sizes[1] / 2;   // 600000
    int NB = (N + 255) / 256;  // 196 scan blocks

    // workspace carve (all offsets stay 16B-aligned: N, E, NB-pad multiples of 4)
    int* hist    = (int*)d_ws;
    int* offsets = hist + N;
    int* cursor  = offsets + N;
    int* csr     = cursor + N;
    float* rdeg  = (float*)(csr + E);
    int* bsum    = (int*)(rdeg + N);
    float* WT1   = (float*)(bsum + ((NB + 3) & ~3));
    float* WT2   = WT1 + D * D;
    float* agg   = WT2 + D * D;

    hipMemsetAsync(hist, 0, (size_t)N * sizeof(int), stream);
    hist_kernel<<<(E + 255) / 256, 256, 0, stream>>>(ei, hist, E);
    partial_kernel<<<NB, 256, 0, stream>>>(hist, bsum, N);
    bscan_kernel<<<1, 256, 0, stream>>>(bsum, NB);
    finalize_kernel<<<NB, 256, 0, stream>>>(hist, bsum, offsets, cursor, rdeg, N);
    fill_kernel<<<(E + 255) / 256, 256, 0, stream>>>(ei, E, cursor, csr);
    transpose2_kernel<<<2, 256, 0, stream>>>(W1, WT1, W2, WT2);

    // round 1
    gather_kernel<<<(N + 3) / 4, 256, 0, stream>>>(x, offsets, hist, csr, rdeg, agg, N);
    linear_kernel<<<(N + TILE_R - 1) / TILE_R, 256, 0, stream>>>(agg, WT1, b1, out, N);
    // round 2 (reads h from d_out, then overwrites d_out)
    gather_kernel<<<(N + 3) / 4, 256, 0, stream>>>(out, offsets, hist, csr, rdeg, agg, N);
    linear_kernel<<<(N + TILE_R - 1) / TILE_R, 256, 0, stream>>>(agg, WT2, b2, out, N);
}

// Round 3
// 240.087 us; speedup vs baseline: 1.5477x; 1.0382x over previous
//
#include <hip/hip_runtime.h>

#define D 128

// ---------------- histogram of row indices ----------------
__global__ __launch_bounds__(256) void hist_kernel(const int* __restrict__ row,
                                                   int* __restrict__ hist, int e) {
    int i = blockIdx.x * blockDim.x + threadIdx.x;
    if (i < e) atomicAdd(&hist[row[i]], 1);
}

// ---------------- phase A: per-block partial sums ----------------
__global__ __launch_bounds__(256) void partial_kernel(const int* __restrict__ hist,
                                                      int* __restrict__ bsum, int n) {
    int i = blockIdx.x * 256 + threadIdx.x;
    int v = (i < n) ? hist[i] : 0;
#pragma unroll
    for (int off = 1; off < 64; off <<= 1) v += __shfl_xor(v, off);
    __shared__ int ws[4];
    int lane = threadIdx.x & 63, w = threadIdx.x >> 6;
    if (lane == 0) ws[w] = v;
    __syncthreads();
    if (threadIdx.x == 0) bsum[blockIdx.x] = ws[0] + ws[1] + ws[2] + ws[3];
}

// ---------------- phase B: exclusive scan of block sums (1 block, nb<=256) ----------------
__global__ __launch_bounds__(256) void bscan_kernel(int* __restrict__ bsum, int nb) {
    int t = threadIdx.x;
    int v = (t < nb) ? bsum[t] : 0;
    int lane = t & 63, w = t >> 6;
    int iv = v;
#pragma unroll
    for (int off = 1; off < 64; off <<= 1) {
        int n2 = __shfl_up(iv, off);
        if (lane >= off) iv += n2;
    }
    __shared__ int wt[4];
    if (lane == 63) wt[w] = iv;
    __syncthreads();
    int add = 0;
    for (int k = 0; k < w; ++k) add += wt[k];
    if (t < nb) bsum[t] = iv + add - v;   // exclusive
}

// ---------------- phase C: per-block exclusive scan + base; emit offsets/cursor/rdeg ----------------
__global__ __launch_bounds__(256) void finalize_kernel(const int* __restrict__ hist,
                                                       const int* __restrict__ bbase,
                                                       int* __restrict__ offsets,
                                                       int* __restrict__ cursor,
                                                       float* __restrict__ rdeg, int n) {
    int i = blockIdx.x * 256 + threadIdx.x;
    int v = (i < n) ? hist[i] : 0;
    int lane = threadIdx.x & 63, w = threadIdx.x >> 6;
    int iv = v;
#pragma unroll
    for (int off = 1; off < 64; off <<= 1) {
        int n2 = __shfl_up(iv, off);
        if (lane >= off) iv += n2;
    }
    __shared__ int wt[4];
    if (lane == 63) wt[w] = iv;
    __syncthreads();
    int add = bbase[blockIdx.x];
    for (int k = 0; k < w; ++k) add += wt[k];
    int excl = iv - v + add;
    if (i < n) {
        offsets[i] = excl;
        cursor[i]  = excl;
        rdeg[i]    = 1.0f / fmaxf((float)v, 1.0f);
    }
}

// ---------------- fill CSR col list via atomic cursors ----------------
__global__ __launch_bounds__(256) void fill_kernel(const int* __restrict__ ei, int e,
                                                   int* __restrict__ cursor,
                                                   int* __restrict__ csr) {
    int i = blockIdx.x * blockDim.x + threadIdx.x;
    if (i < e) {
        int r = ei[i];
        int c = ei[e + i];
        int pos = atomicAdd(&cursor[r], 1);
        csr[pos] = c;
    }
}

// ---------------- transpose both weight matrices (W[j][k] -> WT[k][j]) ----------------
__global__ __launch_bounds__(256) void transpose2_kernel(const float* __restrict__ W1,
                                                         float* __restrict__ WT1,
                                                         const float* __restrict__ W2,
                                                         float* __restrict__ WT2) {
    const float* src = blockIdx.x ? W2 : W1;
    float* dst       = blockIdx.x ? WT2 : WT1;
    for (int i = threadIdx.x; i < D * D; i += 256) {
        int j = i >> 7, k = i & 127;
        dst[k * D + j] = src[i];
    }
}

// ---------------- gather + mean-normalize: agg[n] = rdeg[n] * sum_{c in nbr(n)} src[c] ----------------
// 1 wave per node; lanes 0-31 take even neighbor, 32-63 odd neighbor; float4/lane.
__global__ __launch_bounds__(256) void gather_kernel(const float* __restrict__ src,
                                                     const int* __restrict__ offsets,
                                                     const int* __restrict__ hist,
                                                     const int* __restrict__ csr,
                                                     const float* __restrict__ rdeg,
                                                     float* __restrict__ agg, int n) {
    int wid  = (blockIdx.x * blockDim.x + threadIdx.x) >> 6;
    int lane = threadIdx.x & 63;
    if (wid >= n) return;
    int start = offsets[wid];
    int cnt   = hist[wid];
    int half  = lane >> 5;        // which neighbor of the pair
    int q     = (lane & 31) * 4;  // col offset (float4 granularity)

    float4 acc = make_float4(0.f, 0.f, 0.f, 0.f);
    int i = 0;
    // 4 neighbor rows (2KB) in flight per wave
    for (; i + 4 <= cnt; i += 4) {
        int c0 = csr[start + i + half];
        int c1 = csr[start + i + 2 + half];
        float4 v0 = *(const float4*)&src[(size_t)c0 * D + q];
        float4 v1 = *(const float4*)&src[(size_t)c1 * D + q];
        acc.x += v0.x + v1.x;
        acc.y += v0.y + v1.y;
        acc.z += v0.z + v1.z;
        acc.w += v0.w + v1.w;
    }
    for (; i < cnt; i += 2) {
        int j = i + half;
        if (j < cnt) {
            int c = csr[start + j];
            float4 v = *(const float4*)&src[(size_t)c * D + q];
            acc.x += v.x; acc.y += v.y; acc.z += v.z; acc.w += v.w;
        }
    }
    // combine the two half-wave accumulators
    acc.x += __shfl_xor(acc.x, 32);
    acc.y += __shfl_xor(acc.y, 32);
    acc.z += __shfl_xor(acc.z, 32);
    acc.w += __shfl_xor(acc.w, 32);

    if (half == 0) {
        float r = rdeg[wid];
        float4 res = make_float4(acc.x * r, acc.y * r, acc.z * r, acc.w * r);
        *(float4*)&agg[(size_t)wid * D + q] = res;
    }
}

// ---------------- out[r][j] = relu(bias[j] + sum_k A[r][k] * WT[k][j]) ----------------
#define TILE_R 64
__global__ __launch_bounds__(256) void linear_kernel(const float* __restrict__ A,
                                                     const float* __restrict__ WT,
                                                     const float* __restrict__ bias,
                                                     float* __restrict__ out, int n) {
    __shared__ float As[TILE_R][132];
    int t     = threadIdx.x;
    int rbase = blockIdx.x * TILE_R;
    int rows  = min(TILE_R, n - rbase);

    for (int i = t; i < rows * 32; i += 256) {
        int r = i >> 5, q = i & 31;
        float4 v = *(const float4*)&A[(size_t)(rbase + r) * D + q * 4];
        *(float4*)&As[r][q * 4] = v;
    }
    __syncthreads();

    int jq = t & 31;          // output col group: j = jq*4 .. jq*4+3
    int r0 = (t >> 5) * 8;    // 8 rows per thread

    float4 acc[8];
#pragma unroll
    for (int r = 0; r < 8; ++r) acc[r] = make_float4(0.f, 0.f, 0.f, 0.f);

    const float4* WT4 = (const float4*)WT;
#pragma unroll 4
    for (int k = 0; k < D; k += 2) {
        float4 w0 = WT4[k * 32 + jq];
        float4 w1 = WT4[(k + 1) * 32 + jq];
#pragma unroll
        for (int r = 0; r < 8; ++r) {
            float2 a2 = *(const float2*)&As[r0 + r][k];
            acc[r].x += a2.x * w0.x; acc[r].y += a2.x * w0.y;
            acc[r].z += a2.x * w0.z; acc[r].w += a2.x * w0.w;
            acc[r].x += a2.y * w1.x; acc[r].y += a2.y * w1.y;
            acc[r].z += a2.y * w1.z; acc[r].w += a2.y * w1.w;
        }
    }

    float4 bv = ((const float4*)bias)[jq];
#pragma unroll
    for (int r = 0; r < 8; ++r) {
        int row = rbase + r0 + r;
        if (row < n) {
            float4 o;
            o.x = fmaxf(acc[r].x + bv.x, 0.f);
            o.y = fmaxf(acc[r].y + bv.y, 0.f);
            o.z = fmaxf(acc[r].z + bv.z, 0.f);
            o.w = fmaxf(acc[r].w + bv.w, 0.f);
            *(float4*)&out[(size_t)row * D + jq * 4] = o;
        }
    }
}

extern "C" void kernel_launch(void* const* d_in, const int* in_sizes, int n_in,
                              void* d_out, int out_size, void* d_ws, size_t ws_size,
                              hipStream_t stream) {
    const float* x  = (const float*)d_in[0];
    const int*   ei = (const int*)d_in[1];
    const float* W1 = (const float*)d_in[2];
    const float* b1 = (const float*)d_in[3];
    const float* W2 = (const float*)d_in[4];
    const float* b2 = (const float*)d_in[5];
    float* out = (float*)d_out;

    int N = in_sizes[0] / D;   // 50000
    int E = in_sizes[1] / 2;   // 600000
    int NB = (N + 255) / 256;  // 196 scan blocks

    // workspace carve (all offsets stay 16B-aligned: N, E, NB-pad multiples of 4)
    int* hist    = (int*)d_ws;
    int* offsets = hist + N;
    int* cursor  = offsets + N;
    int* csr     = cursor + N;
    float* rdeg  = (float*)(csr + E);
    int* bsum    = (int*)(rdeg + N);
    float* WT1   = (float*)(bsum + ((NB + 3) & ~3));
    float* WT2   = WT1 + D * D;
    float* agg   = WT2 + D * D;

    hipMemsetAsync(hist, 0, (size_t)N * sizeof(int), stream);
    hist_kernel<<<(E + 255) / 256, 256, 0, stream>>>(ei, hist, E);
    partial_kernel<<<NB, 256, 0, stream>>>(hist, bsum, N);
    bscan_kernel<<<1, 256, 0, stream>>>(bsum, NB);
    finalize_kernel<<<NB, 256, 0, stream>>>(hist, bsum, offsets, cursor, rdeg, N);
    fill_kernel<<<(E + 255) / 256, 256, 0, stream>>>(ei, E, cursor, csr);
    transpose2_kernel<<<2, 256, 0, stream>>>(W1, WT1, W2, WT2);

    // round 1
    gather_kernel<<<(N + 3) / 4, 256, 0, stream>>>(x, offsets, hist, csr, rdeg, agg, N);
    linear_kernel<<<(N + TILE_R - 1) / TILE_R, 256, 0, stream>>>(agg, WT1, b1, out, N);
    // round 2 (reads h from d_out, then overwrites d_out)
    gather_kernel<<<(N + 3) / 4, 256, 0, stream>>>(out, offsets, hist, csr, rdeg, agg, N);
    linear_kernel<<<(N + TILE_R - 1) / TILE_R, 256, 0, stream>>>(agg, WT2, b2, out, N);
}

// Round 4
// 237.900 us; speedup vs baseline: 1.5619x; 1.0092x over previous
//
#include <hip/hip_runtime.h>

#define D 128
#define TILE_R 64

// ---------------- histogram of row indices ----------------
__global__ __launch_bounds__(256) void hist_kernel(const int* __restrict__ row,
                                                   int* __restrict__ hist, int e) {
    int i = blockIdx.x * blockDim.x + threadIdx.x;
    if (i < e) atomicAdd(&hist[row[i]], 1);
}

// ---------------- phase A: per-block partial sums ----------------
__global__ __launch_bounds__(256) void partial_kernel(const int* __restrict__ hist,
                                                      int* __restrict__ bsum, int n) {
    int i = blockIdx.x * 256 + threadIdx.x;
    int v = (i < n) ? hist[i] : 0;
#pragma unroll
    for (int off = 1; off < 64; off <<= 1) v += __shfl_xor(v, off);
    __shared__ int ws[4];
    int lane = threadIdx.x & 63, w = threadIdx.x >> 6;
    if (lane == 0) ws[w] = v;
    __syncthreads();
    if (threadIdx.x == 0) bsum[blockIdx.x] = ws[0] + ws[1] + ws[2] + ws[3];
}

// ---------------- phase B: exclusive scan of block sums (1 block, nb<=256) ----------------
__global__ __launch_bounds__(256) void bscan_kernel(int* __restrict__ bsum, int nb) {
    int t = threadIdx.x;
    int v = (t < nb) ? bsum[t] : 0;
    int lane = t & 63, w = t >> 6;
    int iv = v;
#pragma unroll
    for (int off = 1; off < 64; off <<= 1) {
        int n2 = __shfl_up(iv, off);
        if (lane >= off) iv += n2;
    }
    __shared__ int wt[4];
    if (lane == 63) wt[w] = iv;
    __syncthreads();
    int add = 0;
    for (int k = 0; k < w; ++k) add += wt[k];
    if (t < nb) bsum[t] = iv + add - v;   // exclusive
}

// ---------------- phase C: per-block exclusive scan + base; emit offsets/cursor/rdeg ----------------
__global__ __launch_bounds__(256) void finalize_kernel(const int* __restrict__ hist,
                                                       const int* __restrict__ bbase,
                                                       int* __restrict__ offsets,
                                                       int* __restrict__ cursor,
                                                       float* __restrict__ rdeg, int n) {
    int i = blockIdx.x * 256 + threadIdx.x;
    int v = (i < n) ? hist[i] : 0;
    int lane = threadIdx.x & 63, w = threadIdx.x >> 6;
    int iv = v;
#pragma unroll
    for (int off = 1; off < 64; off <<= 1) {
        int n2 = __shfl_up(iv, off);
        if (lane >= off) iv += n2;
    }
    __shared__ int wt[4];
    if (lane == 63) wt[w] = iv;
    __syncthreads();
    int add = bbase[blockIdx.x];
    for (int k = 0; k < w; ++k) add += wt[k];
    int excl = iv - v + add;
    if (i < n) {
        offsets[i] = excl;
        cursor[i]  = excl;
        rdeg[i]    = 1.0f / fmaxf((float)v, 1.0f);
    }
}

// ---------------- fill CSR col list via atomic cursors ----------------
__global__ __launch_bounds__(256) void fill_kernel(const int* __restrict__ ei, int e,
                                                   int* __restrict__ cursor,
                                                   int* __restrict__ csr) {
    int i = blockIdx.x * blockDim.x + threadIdx.x;
    if (i < e) {
        int r = ei[i];
        int c = ei[e + i];
        int pos = atomicAdd(&cursor[r], 1);
        csr[pos] = c;
    }
}

// ---------------- transpose both weight matrices (W[j][k] -> WT[k][j]) ----------------
__global__ __launch_bounds__(256) void transpose2_kernel(const float* __restrict__ W1,
                                                         float* __restrict__ WT1,
                                                         const float* __restrict__ W2,
                                                         float* __restrict__ WT2) {
    const float* src = blockIdx.x ? W2 : W1;
    float* dst       = blockIdx.x ? WT2 : WT1;
    for (int i = threadIdx.x; i < D * D; i += 256) {
        int j = i >> 7, k = i & 127;
        dst[k * D + j] = src[i];
    }
}

// ---------------- fused: gather+normalize into LDS, then linear+bias+relu ----------------
// Block = 256 threads = 4 waves; tile = 64 nodes; wave wv gathers rows wv*16..wv*16+15.
// Gather: lanes 0-31 even neighbor, 32-63 odd neighbor, float4/lane, 8 rows in flight.
__global__ __launch_bounds__(256) void fused_kernel(const float* __restrict__ src,
                                                    const int* __restrict__ offsets,
                                                    const int* __restrict__ hist,
                                                    const int* __restrict__ csr,
                                                    const float* __restrict__ rdeg,
                                                    const float* __restrict__ WT,
                                                    const float* __restrict__ bias,
                                                    float* __restrict__ out, int n) {
    __shared__ float As[TILE_R][132];
    int t     = threadIdx.x;
    int lane  = t & 63;
    int wv    = t >> 6;            // wave 0..3
    int half  = lane >> 5;         // neighbor parity
    int q     = (lane & 31) * 4;   // col offset (float4)
    int rbase = blockIdx.x * TILE_R;

    // ---- gather phase ----
    for (int r = wv * 16; r < wv * 16 + 16; ++r) {
        int node = rbase + r;
        float4 acc = make_float4(0.f, 0.f, 0.f, 0.f);
        if (node < n) {
            int start = offsets[node];
            int cnt   = hist[node];
            int i = 0;
            for (; i + 8 <= cnt; i += 8) {  // 8 rows (4KB) in flight
                int c0 = csr[start + i + half];
                int c1 = csr[start + i + 2 + half];
                int c2 = csr[start + i + 4 + half];
                int c3 = csr[start + i + 6 + half];
                float4 v0 = *(const float4*)&src[(size_t)c0 * D + q];
                float4 v1 = *(const float4*)&src[(size_t)c1 * D + q];
                float4 v2 = *(const float4*)&src[(size_t)c2 * D + q];
                float4 v3 = *(const float4*)&src[(size_t)c3 * D + q];
                acc.x += (v0.x + v1.x) + (v2.x + v3.x);
                acc.y += (v0.y + v1.y) + (v2.y + v3.y);
                acc.z += (v0.z + v1.z) + (v2.z + v3.z);
                acc.w += (v0.w + v1.w) + (v2.w + v3.w);
            }
            if (i + 4 <= cnt) {
                int c0 = csr[start + i + half];
                int c1 = csr[start + i + 2 + half];
                float4 v0 = *(const float4*)&src[(size_t)c0 * D + q];
                float4 v1 = *(const float4*)&src[(size_t)c1 * D + q];
                acc.x += v0.x + v1.x;
                acc.y += v0.y + v1.y;
                acc.z += v0.z + v1.z;
                acc.w += v0.w + v1.w;
                i += 4;
            }
            for (; i < cnt; i += 2) {
                int j = i + half;
                if (j < cnt) {
                    int c = csr[start + j];
                    float4 v = *(const float4*)&src[(size_t)c * D + q];
                    acc.x += v.x; acc.y += v.y; acc.z += v.z; acc.w += v.w;
                }
            }
            acc.x += __shfl_xor(acc.x, 32);
            acc.y += __shfl_xor(acc.y, 32);
            acc.z += __shfl_xor(acc.z, 32);
            acc.w += __shfl_xor(acc.w, 32);
            float rd = rdeg[node];
            acc.x *= rd; acc.y *= rd; acc.z *= rd; acc.w *= rd;
        }
        if (half == 0) *(float4*)&As[r][q] = acc;
    }
    __syncthreads();

    // ---- linear phase: out[r][j] = relu(bias[j] + sum_k As[r][k]*WT[k][j]) ----
    int jq = t & 31;          // output col group: j = jq*4 .. jq*4+3
    int r0 = (t >> 5) * 8;    // 8 rows per thread

    float4 acc[8];
#pragma unroll
    for (int r = 0; r < 8; ++r) acc[r] = make_float4(0.f, 0.f, 0.f, 0.f);

    const float4* WT4 = (const float4*)WT;
#pragma unroll 4
    for (int k = 0; k < D; k += 2) {
        float4 w0 = WT4[k * 32 + jq];
        float4 w1 = WT4[(k + 1) * 32 + jq];
#pragma unroll
        for (int r = 0; r < 8; ++r) {
            float2 a2 = *(const float2*)&As[r0 + r][k];
            acc[r].x += a2.x * w0.x; acc[r].y += a2.x * w0.y;
            acc[r].z += a2.x * w0.z; acc[r].w += a2.x * w0.w;
            acc[r].x += a2.y * w1.x; acc[r].y += a2.y * w1.y;
            acc[r].z += a2.y * w1.z; acc[r].w += a2.y * w1.w;
        }
    }

    float4 bv = ((const float4*)bias)[jq];
#pragma unroll
    for (int r = 0; r < 8; ++r) {
        int row = rbase + r0 + r;
        if (row < n) {
            float4 o;
            o.x = fmaxf(acc[r].x + bv.x, 0.f);
            o.y = fmaxf(acc[r].y + bv.y, 0.f);
            o.z = fmaxf(acc[r].z + bv.z, 0.f);
            o.w = fmaxf(acc[r].w + bv.w, 0.f);
            *(float4*)&out[(size_t)row * D + jq * 4] = o;
        }
    }
}

extern "C" void kernel_launch(void* const* d_in, const int* in_sizes, int n_in,
                              void* d_out, int out_size, void* d_ws, size_t ws_size,
                              hipStream_t stream) {
    const float* x  = (const float*)d_in[0];
    const int*   ei = (const int*)d_in[1];
    const float* W1 = (const float*)d_in[2];
    const float* b1 = (const float*)d_in[3];
    const float* W2 = (const float*)d_in[4];
    const float* b2 = (const float*)d_in[5];
    float* out = (float*)d_out;

    int N = in_sizes[0] / D;   // 50000
    int E = in_sizes[1] / 2;   // 600000
    int NB = (N + 255) / 256;  // 196 scan blocks

    // workspace carve (all offsets stay 16B-aligned)
    int* hist    = (int*)d_ws;
    int* offsets = hist + N;
    int* cursor  = offsets + N;
    int* csr     = cursor + N;
    float* rdeg  = (float*)(csr + E);
    int* bsum    = (int*)(rdeg + N);
    float* WT1   = (float*)(bsum + ((NB + 3) & ~3));
    float* WT2   = WT1 + D * D;
    float* hbuf  = WT2 + D * D;   // round-1 hidden state [N][D]

    hipMemsetAsync(hist, 0, (size_t)N * sizeof(int), stream);
    hist_kernel<<<(E + 255) / 256, 256, 0, stream>>>(ei, hist, E);
    partial_kernel<<<NB, 256, 0, stream>>>(hist, bsum, N);
    bscan_kernel<<<1, 256, 0, stream>>>(bsum, NB);
    finalize_kernel<<<NB, 256, 0, stream>>>(hist, bsum, offsets, cursor, rdeg, N);
    fill_kernel<<<(E + 255) / 256, 256, 0, stream>>>(ei, E, cursor, csr);
    transpose2_kernel<<<2, 256, 0, stream>>>(W1, WT1, W2, WT2);

    int nblk = (N + TILE_R - 1) / TILE_R;
    // round 1: x -> hbuf
    fused_kernel<<<nblk, 256, 0, stream>>>(x, offsets, hist, csr, rdeg, WT1, b1, hbuf, N);
    // round 2: hbuf -> out
    fused_kernel<<<nblk, 256, 0, stream>>>(hbuf, offsets, hist, csr, rdeg, WT2, b2, out, N);
}

// Round 5
// 219.981 us; speedup vs baseline: 1.6892x; 1.0815x over previous
//
#include <hip/hip_runtime.h>
#include <hip/hip_fp16.h>

#define D 128
#define TILE_R 64

// ---------------- histogram of row indices ----------------
__global__ __launch_bounds__(256) void hist_kernel(const int* __restrict__ row,
                                                   int* __restrict__ hist, int e) {
    int i = blockIdx.x * blockDim.x + threadIdx.x;
    if (i < e) atomicAdd(&hist[row[i]], 1);
}

// ---------------- convert f32 -> fp16, 8 elems/thread ----------------
__global__ __launch_bounds__(256) void cvt_kernel(const float* __restrict__ in,
                                                  __half* __restrict__ out, int n8) {
    int i = blockIdx.x * 256 + threadIdx.x;
    if (i >= n8) return;
    float4 a = ((const float4*)in)[2 * i];
    float4 b = ((const float4*)in)[2 * i + 1];
    __half2 h[4];
    h[0] = __float22half2_rn(make_float2(a.x, a.y));
    h[1] = __float22half2_rn(make_float2(a.z, a.w));
    h[2] = __float22half2_rn(make_float2(b.x, b.y));
    h[3] = __float22half2_rn(make_float2(b.z, b.w));
    ((float4*)out)[i] = *(const float4*)h;
}

// ---------------- phase A: per-block partial sums ----------------
__global__ __launch_bounds__(256) void partial_kernel(const int* __restrict__ hist,
                                                      int* __restrict__ bsum, int n) {
    int i = blockIdx.x * 256 + threadIdx.x;
    int v = (i < n) ? hist[i] : 0;
#pragma unroll
    for (int off = 1; off < 64; off <<= 1) v += __shfl_xor(v, off);
    __shared__ int ws[4];
    int lane = threadIdx.x & 63, w = threadIdx.x >> 6;
    if (lane == 0) ws[w] = v;
    __syncthreads();
    if (threadIdx.x == 0) bsum[blockIdx.x] = ws[0] + ws[1] + ws[2] + ws[3];
}

// ---------------- phase B+C fused: block-prefix of bsum + per-block scan ----------------
__global__ __launch_bounds__(256) void finalize_kernel(const int* __restrict__ hist,
                                                       const int* __restrict__ bsum,
                                                       int* __restrict__ offsets,
                                                       int* __restrict__ cursor,
                                                       float* __restrict__ rdeg, int n) {
    __shared__ int wt[4];
    int t = threadIdx.x, lane = t & 63, w = t >> 6;

    // 1) base = sum of bsum[k] for k < blockIdx.x
    int p = 0;
    for (int k = t; k < blockIdx.x; k += 256) p += bsum[k];
#pragma unroll
    for (int off = 1; off < 64; off <<= 1) p += __shfl_xor(p, off);
    if (lane == 0) wt[w] = p;
    __syncthreads();
    int blockbase = wt[0] + wt[1] + wt[2] + wt[3];
    __syncthreads();

    // 2) per-block exclusive scan of hist
    int i = blockIdx.x * 256 + t;
    int v = (i < n) ? hist[i] : 0;
    int iv = v;
#pragma unroll
    for (int off = 1; off < 64; off <<= 1) {
        int n2 = __shfl_up(iv, off);
        if (lane >= off) iv += n2;
    }
    if (lane == 63) wt[w] = iv;
    __syncthreads();
    int add = blockbase;
    for (int k = 0; k < w; ++k) add += wt[k];
    int excl = iv - v + add;
    if (i < n) {
        offsets[i] = excl;
        cursor[i]  = excl;
        rdeg[i]    = 1.0f / fmaxf((float)v, 1.0f);
    }
}

// ---------------- fill CSR col list via atomic cursors ----------------
__global__ __launch_bounds__(256) void fill_kernel(const int* __restrict__ ei, int e,
                                                   int* __restrict__ cursor,
                                                   int* __restrict__ csr) {
    int i = blockIdx.x * blockDim.x + threadIdx.x;
    if (i < e) {
        int r = ei[i];
        int c = ei[e + i];
        int pos = atomicAdd(&cursor[r], 1);
        csr[pos] = c;
    }
}

// ---------------- transpose both weight matrices (W[j][k] -> WT[k][j]) ----------------
__global__ __launch_bounds__(256) void transpose2_kernel(const float* __restrict__ W1,
                                                         float* __restrict__ WT1,
                                                         const float* __restrict__ W2,
                                                         float* __restrict__ WT2) {
    const float* src = blockIdx.x ? W2 : W1;
    float* dst       = blockIdx.x ? WT2 : WT1;
    for (int i = threadIdx.x; i < D * D; i += 256) {
        int j = i >> 7, k = i & 127;
        dst[k * D + j] = src[i];
    }
}

// ---------------- gather fp16 rows + mean-normalize -> f32 agg ----------------
// 1 wave per node; lanes 0-31 even neighbor, 32-63 odd; 8B (4 halves)/lane; 8 rows in flight.
__device__ inline void addh4(float4& a, float2 v) {
    __half2* h = (__half2*)&v;
    float2 lo = __half22float2(h[0]);
    float2 hi = __half22float2(h[1]);
    a.x += lo.x; a.y += lo.y; a.z += hi.x; a.w += hi.y;
}

__global__ __launch_bounds__(256) void gather_kernel(const __half* __restrict__ src,
                                                     const int* __restrict__ offsets,
                                                     const int* __restrict__ hist,
                                                     const int* __restrict__ csr,
                                                     const float* __restrict__ rdeg,
                                                     float* __restrict__ agg, int n) {
    int wid  = (blockIdx.x * blockDim.x + threadIdx.x) >> 6;
    int lane = threadIdx.x & 63;
    if (wid >= n) return;
    int start = offsets[wid];
    int cnt   = hist[wid];
    int half  = lane >> 5;        // neighbor parity
    int q     = lane & 31;        // 8B group within row (4 halves)

    const float2* base = (const float2*)src;   // row r = float2 index r*32
    float4 acc = make_float4(0.f, 0.f, 0.f, 0.f);
    int i = 0;
    for (; i + 8 <= cnt; i += 8) {   // 8 rows (2KB fp16) in flight
        int c0 = csr[start + i + half];
        int c1 = csr[start + i + 2 + half];
        int c2 = csr[start + i + 4 + half];
        int c3 = csr[start + i + 6 + half];
        float2 v0 = base[(size_t)c0 * 32 + q];
        float2 v1 = base[(size_t)c1 * 32 + q];
        float2 v2 = base[(size_t)c2 * 32 + q];
        float2 v3 = base[(size_t)c3 * 32 + q];
        addh4(acc, v0); addh4(acc, v1); addh4(acc, v2); addh4(acc, v3);
    }
    if (i + 4 <= cnt) {
        int c0 = csr[start + i + half];
        int c1 = csr[start + i + 2 + half];
        float2 v0 = base[(size_t)c0 * 32 + q];
        float2 v1 = base[(size_t)c1 * 32 + q];
        addh4(acc, v0); addh4(acc, v1);
        i += 4;
    }
    for (; i < cnt; i += 2) {
        int j = i + half;
        if (j < cnt) {
            int c = csr[start + j];
            float2 v = base[(size_t)c * 32 + q];
            addh4(acc, v);
        }
    }
    acc.x += __shfl_xor(acc.x, 32);
    acc.y += __shfl_xor(acc.y, 32);
    acc.z += __shfl_xor(acc.z, 32);
    acc.w += __shfl_xor(acc.w, 32);

    if (half == 0) {
        float r = rdeg[wid];
        float4 res = make_float4(acc.x * r, acc.y * r, acc.z * r, acc.w * r);
        *(float4*)&agg[(size_t)wid * D + q * 4] = res;
    }
}

// ---------------- out[r][j] = relu(bias[j] + sum_k A[r][k] * WT[k][j]) ----------------
// OUT_HALF=1 -> write fp16 (for next round's gather); OUT_HALF=0 -> write f32.
template <int OUT_HALF>
__global__ __launch_bounds__(256) void linear_kernel(const float* __restrict__ A,
                                                     const float* __restrict__ WT,
                                                     const float* __restrict__ bias,
                                                     void* __restrict__ outv, int n) {
    __shared__ float As[TILE_R][132];
    int t     = threadIdx.x;
    int rbase = blockIdx.x * TILE_R;
    int rows  = min(TILE_R, n - rbase);

    for (int i = t; i < rows * 32; i += 256) {
        int r = i >> 5, q = i & 31;
        float4 v = *(const float4*)&A[(size_t)(rbase + r) * D + q * 4];
        *(float4*)&As[r][q * 4] = v;
    }
    __syncthreads();

    int jq = t & 31;          // output col group: j = jq*4 .. jq*4+3
    int r0 = (t >> 5) * 8;    // 8 rows per thread

    float4 acc[8];
#pragma unroll
    for (int r = 0; r < 8; ++r) acc[r] = make_float4(0.f, 0.f, 0.f, 0.f);

    const float4* WT4 = (const float4*)WT;
#pragma unroll 4
    for (int k = 0; k < D; k += 2) {
        float4 w0 = WT4[k * 32 + jq];
        float4 w1 = WT4[(k + 1) * 32 + jq];
#pragma unroll
        for (int r = 0; r < 8; ++r) {
            float2 a2 = *(const float2*)&As[r0 + r][k];
            acc[r].x += a2.x * w0.x; acc[r].y += a2.x * w0.y;
            acc[r].z += a2.x * w0.z; acc[r].w += a2.x * w0.w;
            acc[r].x += a2.y * w1.x; acc[r].y += a2.y * w1.y;
            acc[r].z += a2.y * w1.z; acc[r].w += a2.y * w1.w;
        }
    }

    float4 bv = ((const float4*)bias)[jq];
#pragma unroll
    for (int r = 0; r < 8; ++r) {
        int row = rbase + r0 + r;
        if (row < n) {
            float4 o;
            o.x = fmaxf(acc[r].x + bv.x, 0.f);
            o.y = fmaxf(acc[r].y + bv.y, 0.f);
            o.z = fmaxf(acc[r].z + bv.z, 0.f);
            o.w = fmaxf(acc[r].w + bv.w, 0.f);
            if (OUT_HALF) {
                __half2 h[2];
                h[0] = __float22half2_rn(make_float2(o.x, o.y));
                h[1] = __float22half2_rn(make_float2(o.z, o.w));
                *(float2*)&((__half*)outv)[(size_t)row * D + jq * 4] = *(const float2*)h;
            } else {
                *(float4*)&((float*)outv)[(size_t)row * D + jq * 4] = o;
            }
        }
    }
}

extern "C" void kernel_launch(void* const* d_in, const int* in_sizes, int n_in,
                              void* d_out, int out_size, void* d_ws, size_t ws_size,
                              hipStream_t stream) {
    const float* x  = (const float*)d_in[0];
    const int*   ei = (const int*)d_in[1];
    const float* W1 = (const float*)d_in[2];
    const float* b1 = (const float*)d_in[3];
    const float* W2 = (const float*)d_in[4];
    const float* b2 = (const float*)d_in[5];
    float* out = (float*)d_out;

    int N = in_sizes[0] / D;   // 50000
    int E = in_sizes[1] / 2;   // 600000
    int NB = (N + 255) / 256;  // 196 scan blocks

    // workspace carve (all offsets stay 16B-aligned)
    int* hist    = (int*)d_ws;
    int* offsets = hist + N;
    int* cursor  = offsets + N;
    int* csr     = cursor + N;
    float* rdeg  = (float*)(csr + E);
    int* bsum    = (int*)(rdeg + N);
    float* WT1   = (float*)(bsum + ((NB + 3) & ~3));
    float* WT2   = WT1 + D * D;
    __half* xh   = (__half*)(WT2 + D * D);   // x in fp16 [N][D]
    __half* hh   = xh + (size_t)N * D;       // round-1 hidden in fp16 [N][D]
    float* agg   = out;                      // agg lives in d_out (race-free per-block)

    hipMemsetAsync(hist, 0, (size_t)N * sizeof(int), stream);
    cvt_kernel<<<(N * D / 8 + 255) / 256, 256, 0, stream>>>(x, xh, N * D / 8);
    hist_kernel<<<(E + 255) / 256, 256, 0, stream>>>(ei, hist, E);
    partial_kernel<<<NB, 256, 0, stream>>>(hist, bsum, N);
    finalize_kernel<<<NB, 256, 0, stream>>>(hist, bsum, offsets, cursor, rdeg, N);
    fill_kernel<<<(E + 255) / 256, 256, 0, stream>>>(ei, E, cursor, csr);
    transpose2_kernel<<<2, 256, 0, stream>>>(W1, WT1, W2, WT2);

    int nblk = (N + TILE_R - 1) / TILE_R;
    // round 1: gather(xh) -> agg(=out), linear -> hh (fp16)
    gather_kernel<<<(N + 3) / 4, 256, 0, stream>>>(xh, offsets, hist, csr, rdeg, agg, N);
    linear_kernel<1><<<nblk, 256, 0, stream>>>(agg, WT1, b1, hh, N);
    // round 2: gather(hh) -> agg(=out), linear -> out (f32)
    gather_kernel<<<(N + 3) / 4, 256, 0, stream>>>(hh, offsets, hist, csr, rdeg, agg, N);
    linear_kernel<0><<<nblk, 256, 0, stream>>>(agg, WT2, b2, out, N);
}

// Round 6
// 212.761 us; speedup vs baseline: 1.7465x; 1.0339x over previous
//
#include <hip/hip_runtime.h>
#include <hip/hip_fp16.h>

#define D 128
#define TILE_R 64

// ---------------- convert f32 -> fp16 (8 elems/thread) AND zero hist ----------------
__global__ __launch_bounds__(256) void cvt_kernel(const float* __restrict__ in,
                                                  __half* __restrict__ out, int n8,
                                                  int* __restrict__ hist, int n) {
    int i = blockIdx.x * 256 + threadIdx.x;
    if (i < n) hist[i] = 0;            // fold the memset in (saves a 40us rocclr fill)
    if (i >= n8) return;
    float4 a = ((const float4*)in)[2 * i];
    float4 b = ((const float4*)in)[2 * i + 1];
    __half2 h[4];
    h[0] = __float22half2_rn(make_float2(a.x, a.y));
    h[1] = __float22half2_rn(make_float2(a.z, a.w));
    h[2] = __float22half2_rn(make_float2(b.x, b.y));
    h[3] = __float22half2_rn(make_float2(b.z, b.w));
    ((float4*)out)[i] = *(const float4*)h;
}

// ---------------- histogram of row indices ----------------
__global__ __launch_bounds__(256) void hist_kernel(const int* __restrict__ row,
                                                   int* __restrict__ hist, int e) {
    int i = blockIdx.x * blockDim.x + threadIdx.x;
    if (i < e) atomicAdd(&hist[row[i]], 1);
}

// ---------------- phase A: per-block partial sums ----------------
__global__ __launch_bounds__(256) void partial_kernel(const int* __restrict__ hist,
                                                      int* __restrict__ bsum, int n) {
    int i = blockIdx.x * 256 + threadIdx.x;
    int v = (i < n) ? hist[i] : 0;
#pragma unroll
    for (int off = 1; off < 64; off <<= 1) v += __shfl_xor(v, off);
    __shared__ int ws[4];
    int lane = threadIdx.x & 63, w = threadIdx.x >> 6;
    if (lane == 0) ws[w] = v;
    __syncthreads();
    if (threadIdx.x == 0) bsum[blockIdx.x] = ws[0] + ws[1] + ws[2] + ws[3];
}

// ---------------- phase B+C fused: block-prefix of bsum + per-block scan ----------------
__global__ __launch_bounds__(256) void finalize_kernel(const int* __restrict__ hist,
                                                       const int* __restrict__ bsum,
                                                       int* __restrict__ offsets,
                                                       int* __restrict__ cursor,
                                                       float* __restrict__ rdeg, int n) {
    __shared__ int wt[4];
    int t = threadIdx.x, lane = t & 63, w = t >> 6;

    int p = 0;
    for (int k = t; k < blockIdx.x; k += 256) p += bsum[k];
#pragma unroll
    for (int off = 1; off < 64; off <<= 1) p += __shfl_xor(p, off);
    if (lane == 0) wt[w] = p;
    __syncthreads();
    int blockbase = wt[0] + wt[1] + wt[2] + wt[3];
    __syncthreads();

    int i = blockIdx.x * 256 + t;
    int v = (i < n) ? hist[i] : 0;
    int iv = v;
#pragma unroll
    for (int off = 1; off < 64; off <<= 1) {
        int n2 = __shfl_up(iv, off);
        if (lane >= off) iv += n2;
    }
    if (lane == 63) wt[w] = iv;
    __syncthreads();
    int add = blockbase;
    for (int k = 0; k < w; ++k) add += wt[k];
    int excl = iv - v + add;
    if (i < n) {
        offsets[i] = excl;
        cursor[i]  = excl;
        rdeg[i]    = 1.0f / fmaxf((float)v, 1.0f);
    }
}

// ---------------- fill CSR col list via atomic cursors ----------------
__global__ __launch_bounds__(256) void fill_kernel(const int* __restrict__ ei, int e,
                                                   int* __restrict__ cursor,
                                                   int* __restrict__ csr) {
    int i = blockIdx.x * blockDim.x + threadIdx.x;
    if (i < e) {
        int r = ei[i];
        int c = ei[e + i];
        int pos = atomicAdd(&cursor[r], 1);
        csr[pos] = c;
    }
}

// ---------------- transpose both weight matrices (W[j][k] -> WT[k][j]) ----------------
__global__ __launch_bounds__(256) void transpose2_kernel(const float* __restrict__ W1,
                                                         float* __restrict__ WT1,
                                                         const float* __restrict__ W2,
                                                         float* __restrict__ WT2) {
    const float* src = blockIdx.x ? W2 : W1;
    float* dst       = blockIdx.x ? WT2 : WT1;
    for (int i = threadIdx.x; i < D * D; i += 256) {
        int j = i >> 7, k = i & 127;
        dst[k * D + j] = src[i];
    }
}

// ---------------- z[r][j] = sum_k src[r][k] * WT[k][j]  (fp16 in, fp16 out, no bias) ----------------
__global__ __launch_bounds__(256) void linear_kernel(const __half* __restrict__ src,
                                                     const float* __restrict__ WT,
                                                     __half* __restrict__ z, int n) {
    __shared__ float As[TILE_R][132];
    int t     = threadIdx.x;
    int rbase = blockIdx.x * TILE_R;
    int rows  = min(TILE_R, n - rbase);

    // stage fp16 tile -> f32 LDS (8 halves per float4 load)
    for (int i = t; i < rows * 16; i += 256) {
        int r = i >> 4, g = i & 15;
        float4 raw = *(const float4*)&src[(size_t)(rbase + r) * D + g * 8];
        const __half2* h = (const __half2*)&raw;
        float2 f0 = __half22float2(h[0]);
        float2 f1 = __half22float2(h[1]);
        float2 f2 = __half22float2(h[2]);
        float2 f3 = __half22float2(h[3]);
        *(float4*)&As[r][g * 8]     = make_float4(f0.x, f0.y, f1.x, f1.y);
        *(float4*)&As[r][g * 8 + 4] = make_float4(f2.x, f2.y, f3.x, f3.y);
    }
    __syncthreads();

    int jq = t & 31;          // output col group: j = jq*4 .. jq*4+3
    int r0 = (t >> 5) * 8;    // 8 rows per thread

    float4 acc[8];
#pragma unroll
    for (int r = 0; r < 8; ++r) acc[r] = make_float4(0.f, 0.f, 0.f, 0.f);

    const float4* WT4 = (const float4*)WT;
#pragma unroll 4
    for (int k = 0; k < D; k += 2) {
        float4 w0 = WT4[k * 32 + jq];
        float4 w1 = WT4[(k + 1) * 32 + jq];
#pragma unroll
        for (int r = 0; r < 8; ++r) {
            float2 a2 = *(const float2*)&As[r0 + r][k];
            acc[r].x += a2.x * w0.x; acc[r].y += a2.x * w0.y;
            acc[r].z += a2.x * w0.z; acc[r].w += a2.x * w0.w;
            acc[r].x += a2.y * w1.x; acc[r].y += a2.y * w1.y;
            acc[r].z += a2.y * w1.z; acc[r].w += a2.y * w1.w;
        }
    }

#pragma unroll
    for (int r = 0; r < 8; ++r) {
        int row = rbase + r0 + r;
        if (row < n) {
            __half2 h[2];
            h[0] = __float22half2_rn(make_float2(acc[r].x, acc[r].y));
            h[1] = __float22half2_rn(make_float2(acc[r].z, acc[r].w));
            *(float2*)&z[(size_t)row * D + jq * 4] = *(const float2*)h;
        }
    }
}

// ---------------- gather z rows, mean-normalize, +bias, relu -> round output ----------------
// 1 wave per node; lanes 0-31 even neighbor, 32-63 odd; 8B (4 halves)/lane; 8 rows in flight.
__device__ inline void addh4(float4& a, float2 v) {
    const __half2* h = (const __half2*)&v;
    float2 lo = __half22float2(h[0]);
    float2 hi = __half22float2(h[1]);
    a.x += lo.x; a.y += lo.y; a.z += hi.x; a.w += hi.y;
}

template <int OUT_HALF>
__global__ __launch_bounds__(256) void gather_kernel(const __half* __restrict__ z,
                                                     const int* __restrict__ offsets,
                                                     const int* __restrict__ hist,
                                                     const int* __restrict__ csr,
                                                     const float* __restrict__ rdeg,
                                                     const float* __restrict__ bias,
                                                     void* __restrict__ outv, int n) {
    int wid  = (blockIdx.x * blockDim.x + threadIdx.x) >> 6;
    int lane = threadIdx.x & 63;
    if (wid >= n) return;
    int start = offsets[wid];
    int cnt   = hist[wid];
    int half  = lane >> 5;        // neighbor parity
    int q     = lane & 31;        // 8B group within row (4 halves)

    const float2* base = (const float2*)z;   // row r = float2 index r*32
    float4 acc = make_float4(0.f, 0.f, 0.f, 0.f);
    int i = 0;
    for (; i + 8 <= cnt; i += 8) {   // 8 rows (2KB fp16) in flight
        int c0 = csr[start + i + half];
        int c1 = csr[start + i + 2 + half];
        int c2 = csr[start + i + 4 + half];
        int c3 = csr[start + i + 6 + half];
        float2 v0 = base[(size_t)c0 * 32 + q];
        float2 v1 = base[(size_t)c1 * 32 + q];
        float2 v2 = base[(size_t)c2 * 32 + q];
        float2 v3 = base[(size_t)c3 * 32 + q];
        addh4(acc, v0); addh4(acc, v1); addh4(acc, v2); addh4(acc, v3);
    }
    if (i + 4 <= cnt) {
        int c0 = csr[start + i + half];
        int c1 = csr[start + i + 2 + half];
        float2 v0 = base[(size_t)c0 * 32 + q];
        float2 v1 = base[(size_t)c1 * 32 + q];
        addh4(acc, v0); addh4(acc, v1);
        i += 4;
    }
    for (; i < cnt; i += 2) {
        int j = i + half;
        if (j < cnt) {
            int c = csr[start + j];
            float2 v = base[(size_t)c * 32 + q];
            addh4(acc, v);
        }
    }
    acc.x += __shfl_xor(acc.x, 32);
    acc.y += __shfl_xor(acc.y, 32);
    acc.z += __shfl_xor(acc.z, 32);
    acc.w += __shfl_xor(acc.w, 32);

    if (half == 0) {
        float rd = rdeg[wid];
        float4 bv = ((const float4*)bias)[q];
        float4 o;
        o.x = fmaxf(acc.x * rd + bv.x, 0.f);
        o.y = fmaxf(acc.y * rd + bv.y, 0.f);
        o.z = fmaxf(acc.z * rd + bv.z, 0.f);
        o.w = fmaxf(acc.w * rd + bv.w, 0.f);
        if (OUT_HALF) {
            __half2 h[2];
            h[0] = __float22half2_rn(make_float2(o.x, o.y));
            h[1] = __float22half2_rn(make_float2(o.z, o.w));
            *(float2*)&((__half*)outv)[(size_t)wid * D + q * 4] = *(const float2*)h;
        } else {
            *(float4*)&((float*)outv)[(size_t)wid * D + q * 4] = o;
        }
    }
}

extern "C" void kernel_launch(void* const* d_in, const int* in_sizes, int n_in,
                              void* d_out, int out_size, void* d_ws, size_t ws_size,
                              hipStream_t stream) {
    const float* x  = (const float*)d_in[0];
    const int*   ei = (const int*)d_in[1];
    const float* W1 = (const float*)d_in[2];
    const float* b1 = (const float*)d_in[3];
    const float* W2 = (const float*)d_in[4];
    const float* b2 = (const float*)d_in[5];
    float* out = (float*)d_out;

    int N = in_sizes[0] / D;   // 50000
    int E = in_sizes[1] / 2;   // 600000
    int NB = (N + 255) / 256;  // 196 scan blocks

    // workspace carve (all offsets stay 16B-aligned)
    int* hist    = (int*)d_ws;
    int* offsets = hist + N;
    int* cursor  = offsets + N;
    int* csr     = cursor + N;
    float* rdeg  = (float*)(csr + E);
    int* bsum    = (int*)(rdeg + N);
    float* WT1   = (float*)(bsum + ((NB + 3) & ~3));
    float* WT2   = WT1 + D * D;
    __half* xh   = (__half*)(WT2 + D * D);   // x in fp16 [N][D]
    __half* hh   = xh + (size_t)N * D;       // round-1 output h in fp16 [N][D]
    __half* zz   = hh + (size_t)N * D;       // per-round z = src @ W^T in fp16 [N][D]

    cvt_kernel<<<(N * D / 8 + 255) / 256, 256, 0, stream>>>(x, xh, N * D / 8, hist, N);
    hist_kernel<<<(E + 255) / 256, 256, 0, stream>>>(ei, hist, E);
    partial_kernel<<<NB, 256, 0, stream>>>(hist, bsum, N);
    finalize_kernel<<<NB, 256, 0, stream>>>(hist, bsum, offsets, cursor, rdeg, N);
    fill_kernel<<<(E + 255) / 256, 256, 0, stream>>>(ei, E, cursor, csr);
    transpose2_kernel<<<2, 256, 0, stream>>>(W1, WT1, W2, WT2);

    int nblk = (N + TILE_R - 1) / TILE_R;
    // round 1: z1 = xh @ W1^T ; h = relu(S z1 + b1) -> hh (fp16)
    linear_kernel<<<nblk, 256, 0, stream>>>(xh, WT1, zz, N);
    gather_kernel<1><<<(N + 3) / 4, 256, 0, stream>>>(zz, offsets, hist, csr, rdeg, b1, hh, N);
    // round 2: z2 = hh @ W2^T ; out = relu(S z2 + b2) -> f32 out
    linear_kernel<<<nblk, 256, 0, stream>>>(hh, WT2, zz, N);
    gather_kernel<0><<<(N + 3) / 4, 256, 0, stream>>>(zz, offsets, hist, csr, rdeg, b2, out, N);
}

// Round 7
// 206.626 us; speedup vs baseline: 1.7983x; 1.0297x over previous
//
#include <hip/hip_runtime.h>
#include <hip/hip_fp16.h>

#define D 128
#define TILE_R 64

// ---------------- prep: f32->fp16 convert + zero hist + transpose W1/W2 ----------------
// blocks 0,1: transpose W1/W2 (W[j][k] -> WT[k][j]); blocks 2..: cvt 8 elems/thread + hist zero
__global__ __launch_bounds__(256) void prep_kernel(const float* __restrict__ in,
                                                   __half* __restrict__ out, int n8,
                                                   int* __restrict__ hist, int n,
                                                   const float* __restrict__ W1,
                                                   float* __restrict__ WT1,
                                                   const float* __restrict__ W2,
                                                   float* __restrict__ WT2) {
    if (blockIdx.x < 2) {
        const float* src = blockIdx.x ? W2 : W1;
        float* dst       = blockIdx.x ? WT2 : WT1;
        for (int i = threadIdx.x; i < D * D; i += 256) {
            int j = i >> 7, k = i & 127;
            dst[k * D + j] = src[i];
        }
        return;
    }
    int i = (blockIdx.x - 2) * 256 + threadIdx.x;
    if (i < n) hist[i] = 0;
    if (i >= n8) return;
    float4 a = ((const float4*)in)[2 * i];
    float4 b = ((const float4*)in)[2 * i + 1];
    __half2 h[4];
    h[0] = __float22half2_rn(make_float2(a.x, a.y));
    h[1] = __float22half2_rn(make_float2(a.z, a.w));
    h[2] = __float22half2_rn(make_float2(b.x, b.y));
    h[3] = __float22half2_rn(make_float2(b.z, b.w));
    ((float4*)out)[i] = *(const float4*)h;
}

// ---------------- histogram of row indices ----------------
__global__ __launch_bounds__(256) void hist_kernel(const int* __restrict__ row,
                                                   int* __restrict__ hist, int e) {
    int i = blockIdx.x * blockDim.x + threadIdx.x;
    if (i < e) atomicAdd(&hist[row[i]], 1);
}

// ---------------- phase A: per-block partial sums ----------------
__global__ __launch_bounds__(256) void partial_kernel(const int* __restrict__ hist,
                                                      int* __restrict__ bsum, int n) {
    int i = blockIdx.x * 256 + threadIdx.x;
    int v = (i < n) ? hist[i] : 0;
#pragma unroll
    for (int off = 1; off < 64; off <<= 1) v += __shfl_xor(v, off);
    __shared__ int ws[4];
    int lane = threadIdx.x & 63, w = threadIdx.x >> 6;
    if (lane == 0) ws[w] = v;
    __syncthreads();
    if (threadIdx.x == 0) bsum[blockIdx.x] = ws[0] + ws[1] + ws[2] + ws[3];
}

// ---------------- phase B+C fused: block-prefix of bsum + per-block scan ----------------
__global__ __launch_bounds__(256) void finalize_kernel(const int* __restrict__ hist,
                                                       const int* __restrict__ bsum,
                                                       int* __restrict__ offsets,
                                                       int* __restrict__ cursor,
                                                       float* __restrict__ rdeg, int n) {
    __shared__ int wt[4];
    int t = threadIdx.x, lane = t & 63, w = t >> 6;

    int p = 0;
    for (int k = t; k < blockIdx.x; k += 256) p += bsum[k];
#pragma unroll
    for (int off = 1; off < 64; off <<= 1) p += __shfl_xor(p, off);
    if (lane == 0) wt[w] = p;
    __syncthreads();
    int blockbase = wt[0] + wt[1] + wt[2] + wt[3];
    __syncthreads();

    int i = blockIdx.x * 256 + t;
    int v = (i < n) ? hist[i] : 0;
    int iv = v;
#pragma unroll
    for (int off = 1; off < 64; off <<= 1) {
        int n2 = __shfl_up(iv, off);
        if (lane >= off) iv += n2;
    }
    if (lane == 63) wt[w] = iv;
    __syncthreads();
    int add = blockbase;
    for (int k = 0; k < w; ++k) add += wt[k];
    int excl = iv - v + add;
    if (i < n) {
        offsets[i] = excl;
        cursor[i]  = excl;
        rdeg[i]    = 1.0f / fmaxf((float)v, 1.0f);
    }
}

// ---------------- fill CSR col list via atomic cursors ----------------
__global__ __launch_bounds__(256) void fill_kernel(const int* __restrict__ ei, int e,
                                                   int* __restrict__ cursor,
                                                   int* __restrict__ csr) {
    int i = blockIdx.x * blockDim.x + threadIdx.x;
    if (i < e) {
        int r = ei[i];
        int c = ei[e + i];
        int pos = atomicAdd(&cursor[r], 1);
        csr[pos] = c;
    }
}

// ---------------- z[r][j] = sum_k src[r][k] * WT[k][j]  (fp16 in, fp16 out, no bias) ----------------
__global__ __launch_bounds__(256) void linear_kernel(const __half* __restrict__ src,
                                                     const float* __restrict__ WT,
                                                     __half* __restrict__ z, int n) {
    __shared__ float As[TILE_R][132];
    int t     = threadIdx.x;
    int rbase = blockIdx.x * TILE_R;
    int rows  = min(TILE_R, n - rbase);

    // stage fp16 tile -> f32 LDS (8 halves per float4 load)
    for (int i = t; i < rows * 16; i += 256) {
        int r = i >> 4, g = i & 15;
        float4 raw = *(const float4*)&src[(size_t)(rbase + r) * D + g * 8];
        const __half2* h = (const __half2*)&raw;
        float2 f0 = __half22float2(h[0]);
        float2 f1 = __half22float2(h[1]);
        float2 f2 = __half22float2(h[2]);
        float2 f3 = __half22float2(h[3]);
        *(float4*)&As[r][g * 8]     = make_float4(f0.x, f0.y, f1.x, f1.y);
        *(float4*)&As[r][g * 8 + 4] = make_float4(f2.x, f2.y, f3.x, f3.y);
    }
    __syncthreads();

    int jq = t & 31;          // output col group: j = jq*4 .. jq*4+3
    int r0 = (t >> 5) * 8;    // 8 rows per thread

    float4 acc[8];
#pragma unroll
    for (int r = 0; r < 8; ++r) acc[r] = make_float4(0.f, 0.f, 0.f, 0.f);

    const float4* WT4 = (const float4*)WT;
#pragma unroll 4
    for (int k = 0; k < D; k += 2) {
        float4 w0 = WT4[k * 32 + jq];
        float4 w1 = WT4[(k + 1) * 32 + jq];
#pragma unroll
        for (int r = 0; r < 8; ++r) {
            float2 a2 = *(const float2*)&As[r0 + r][k];
            acc[r].x += a2.x * w0.x; acc[r].y += a2.x * w0.y;
            acc[r].z += a2.x * w0.z; acc[r].w += a2.x * w0.w;
            acc[r].x += a2.y * w1.x; acc[r].y += a2.y * w1.y;
            acc[r].z += a2.y * w1.z; acc[r].w += a2.y * w1.w;
        }
    }

#pragma unroll
    for (int r = 0; r < 8; ++r) {
        int row = rbase + r0 + r;
        if (row < n) {
            __half2 h[2];
            h[0] = __float22half2_rn(make_float2(acc[r].x, acc[r].y));
            h[1] = __float22half2_rn(make_float2(acc[r].z, acc[r].w));
            *(float2*)&z[(size_t)row * D + jq * 4] = *(const float2*)h;
        }
    }
}

// ---------------- gather z rows, mean-normalize, +bias, relu -> round output ----------------
// 4 nodes per wave: 16-lane group per node, each lane loads float4 (8 halves) of the 256B row.
// No cross-lane reduce. 8-deep unroll -> up to 32 independent row-loads in flight per wave.
__device__ inline void addh8(float* a, float4 v) {
    const __half2* h = (const __half2*)&v;
    float2 f0 = __half22float2(h[0]);
    float2 f1 = __half22float2(h[1]);
    float2 f2 = __half22float2(h[2]);
    float2 f3 = __half22float2(h[3]);
    a[0] += f0.x; a[1] += f0.y; a[2] += f1.x; a[3] += f1.y;
    a[4] += f2.x; a[5] += f2.y; a[6] += f3.x; a[7] += f3.y;
}

template <int OUT_HALF>
__global__ __launch_bounds__(256) void gather_kernel(const __half* __restrict__ z,
                                                     const int* __restrict__ offsets,
                                                     const int* __restrict__ hist,
                                                     const int* __restrict__ csr,
                                                     const float* __restrict__ rdeg,
                                                     const float* __restrict__ bias,
                                                     void* __restrict__ outv, int n) {
    int tid  = blockIdx.x * 256 + threadIdx.x;
    int wave = tid >> 6;
    int lane = threadIdx.x & 63;
    int g    = lane >> 4;         // group 0..3 -> node
    int gl   = lane & 15;         // lane in group -> 16B slice of row
    int node = wave * 4 + g;
    if (node >= n) return;

    int start = offsets[node];
    int cnt   = hist[node];
    const float4* base = (const float4*)z;   // row r = float4 index r*16 + gl

    float acc[8] = {0.f, 0.f, 0.f, 0.f, 0.f, 0.f, 0.f, 0.f};
    int i = 0;
    for (; i + 8 <= cnt; i += 8) {
        int c0 = csr[start + i];
        int c1 = csr[start + i + 1];
        int c2 = csr[start + i + 2];
        int c3 = csr[start + i + 3];
        int c4 = csr[start + i + 4];
        int c5 = csr[start + i + 5];
        int c6 = csr[start + i + 6];
        int c7 = csr[start + i + 7];
        float4 v0 = base[(size_t)c0 * 16 + gl];
        float4 v1 = base[(size_t)c1 * 16 + gl];
        float4 v2 = base[(size_t)c2 * 16 + gl];
        float4 v3 = base[(size_t)c3 * 16 + gl];
        float4 v4 = base[(size_t)c4 * 16 + gl];
        float4 v5 = base[(size_t)c5 * 16 + gl];
        float4 v6 = base[(size_t)c6 * 16 + gl];
        float4 v7 = base[(size_t)c7 * 16 + gl];
        addh8(acc, v0); addh8(acc, v1); addh8(acc, v2); addh8(acc, v3);
        addh8(acc, v4); addh8(acc, v5); addh8(acc, v6); addh8(acc, v7);
    }
    if (i + 4 <= cnt) {
        int c0 = csr[start + i];
        int c1 = csr[start + i + 1];
        int c2 = csr[start + i + 2];
        int c3 = csr[start + i + 3];
        float4 v0 = base[(size_t)c0 * 16 + gl];
        float4 v1 = base[(size_t)c1 * 16 + gl];
        float4 v2 = base[(size_t)c2 * 16 + gl];
        float4 v3 = base[(size_t)c3 * 16 + gl];
        addh8(acc, v0); addh8(acc, v1); addh8(acc, v2); addh8(acc, v3);
        i += 4;
    }
    int rem = cnt - i;   // 0..3
    if (rem > 0) {
        // clamped indices: all loads issue immediately, adds are predicated
        int c0 = csr[start + i];
        int c1 = csr[start + min(i + 1, cnt - 1)];
        int c2 = csr[start + min(i + 2, cnt - 1)];
        float4 v0 = base[(size_t)c0 * 16 + gl];
        float4 v1 = base[(size_t)c1 * 16 + gl];
        float4 v2 = base[(size_t)c2 * 16 + gl];
        addh8(acc, v0);
        if (rem > 1) addh8(acc, v1);
        if (rem > 2) addh8(acc, v2);
    }

    float rd = rdeg[node];
    float4 b0 = ((const float4*)bias)[gl * 2];
    float4 b1 = ((const float4*)bias)[gl * 2 + 1];
    float o[8];
    o[0] = fmaxf(acc[0] * rd + b0.x, 0.f);
    o[1] = fmaxf(acc[1] * rd + b0.y, 0.f);
    o[2] = fmaxf(acc[2] * rd + b0.z, 0.f);
    o[3] = fmaxf(acc[3] * rd + b0.w, 0.f);
    o[4] = fmaxf(acc[4] * rd + b1.x, 0.f);
    o[5] = fmaxf(acc[5] * rd + b1.y, 0.f);
    o[6] = fmaxf(acc[6] * rd + b1.z, 0.f);
    o[7] = fmaxf(acc[7] * rd + b1.w, 0.f);

    if (OUT_HALF) {
        __half2 h[4];
        h[0] = __float22half2_rn(make_float2(o[0], o[1]));
        h[1] = __float22half2_rn(make_float2(o[2], o[3]));
        h[2] = __float22half2_rn(make_float2(o[4], o[5]));
        h[3] = __float22half2_rn(make_float2(o[6], o[7]));
        ((float4*)outv)[(size_t)node * 16 + gl] = *(const float4*)h;
    } else {
        float4* o4 = (float4*)outv;
        o4[(size_t)node * 32 + gl * 2]     = make_float4(o[0], o[1], o[2], o[3]);
        o4[(size_t)node * 32 + gl * 2 + 1] = make_float4(o[4], o[5], o[6], o[7]);
    }
}

extern "C" void kernel_launch(void* const* d_in, const int* in_sizes, int n_in,
                              void* d_out, int out_size, void* d_ws, size_t ws_size,
                              hipStream_t stream) {
    const float* x  = (const float*)d_in[0];
    const int*   ei = (const int*)d_in[1];
    const float* W1 = (const float*)d_in[2];
    const float* b1 = (const float*)d_in[3];
    const float* W2 = (const float*)d_in[4];
    const float* b2 = (const float*)d_in[5];
    float* out = (float*)d_out;

    int N = in_sizes[0] / D;   // 50000
    int E = in_sizes[1] / 2;   // 600000
    int NB = (N + 255) / 256;  // 196 scan blocks

    // workspace carve (all offsets stay 16B-aligned)
    int* hist    = (int*)d_ws;
    int* offsets = hist + N;
    int* cursor  = offsets + N;
    int* csr     = cursor + N;
    float* rdeg  = (float*)(csr + E);
    int* bsum    = (int*)(rdeg + N);
    float* WT1   = (float*)(bsum + ((NB + 3) & ~3));
    float* WT2   = WT1 + D * D;
    __half* xh   = (__half*)(WT2 + D * D);   // x in fp16 [N][D]
    __half* hh   = xh + (size_t)N * D;       // round-1 output h in fp16 [N][D]
    __half* zz   = hh + (size_t)N * D;       // per-round z = src @ W^T in fp16 [N][D]

    prep_kernel<<<(N * D / 8 + 255) / 256 + 2, 256, 0, stream>>>(x, xh, N * D / 8, hist, N,
                                                                 W1, WT1, W2, WT2);
    hist_kernel<<<(E + 255) / 256, 256, 0, stream>>>(ei, hist, E);
    partial_kernel<<<NB, 256, 0, stream>>>(hist, bsum, N);
    finalize_kernel<<<NB, 256, 0, stream>>>(hist, bsum, offsets, cursor, rdeg, N);
    fill_kernel<<<(E + 255) / 256, 256, 0, stream>>>(ei, E, cursor, csr);

    int nblk  = (N + TILE_R - 1) / TILE_R;
    int gblk  = ((N + 3) / 4 * 64 + 255) / 256;   // 4 nodes per wave
    // round 1: z1 = xh @ W1^T ; h = relu(S z1 + b1) -> hh (fp16)
    linear_kernel<<<nblk, 256, 0, stream>>>(xh, WT1, zz, N);
    gather_kernel<1><<<gblk, 256, 0, stream>>>(zz, offsets, hist, csr, rdeg, b1, hh, N);
    // round 2: z2 = hh @ W2^T ; out = relu(S z2 + b2) -> f32 out
    linear_kernel<<<nblk, 256, 0, stream>>>(hh, WT2, zz, N);
    gather_kernel<0><<<gblk, 256, 0, stream>>>(zz, offsets, hist, csr, rdeg, b2, out, N);
}

// Round 8
// 167.093 us; speedup vs baseline: 2.2238x; 1.2366x over previous
//
#include <hip/hip_runtime.h>
#include <hip/hip_fp16.h>

#define D 128
#define TILE_R 64

typedef _Float16 h8 __attribute__((ext_vector_type(8)));
typedef float f4 __attribute__((ext_vector_type(4)));

// ---------------- prep: f32->fp16 convert + zero hist + build MFMA-swizzled W buffers ----------------
// blocks 0,1: build WB (fp16, fragment-ready order) for W1/W2; blocks 2..: cvt + hist zero.
// WB[idx], idx = ((c*4+kk)*64 + l)*8 + j  holds  WT[kk*32+(l>>4)*8+j][c*16+(l&15)] = W[col][k].
__global__ __launch_bounds__(256) void prep_kernel(const float* __restrict__ in,
                                                   __half* __restrict__ out, int n8,
                                                   int* __restrict__ hist, int n,
                                                   const float* __restrict__ W1,
                                                   __half* __restrict__ WB1,
                                                   const float* __restrict__ W2,
                                                   __half* __restrict__ WB2) {
    if (blockIdx.x < 2) {
        const float* W = blockIdx.x ? W2 : W1;
        __half* WB     = blockIdx.x ? WB2 : WB1;
        for (int idx = threadIdx.x; idx < D * D; idx += 256) {
            int j  = idx & 7;
            int l  = (idx >> 3) & 63;
            int kk = (idx >> 9) & 3;
            int c  = idx >> 11;
            int k   = kk * 32 + (l >> 4) * 8 + j;
            int col = c * 16 + (l & 15);
            WB[idx] = __float2half(W[col * D + k]);
        }
        return;
    }
    int i = (blockIdx.x - 2) * 256 + threadIdx.x;
    if (i < n) hist[i] = 0;
    if (i >= n8) return;
    float4 a = ((const float4*)in)[2 * i];
    float4 b = ((const float4*)in)[2 * i + 1];
    __half2 h[4];
    h[0] = __float22half2_rn(make_float2(a.x, a.y));
    h[1] = __float22half2_rn(make_float2(a.z, a.w));
    h[2] = __float22half2_rn(make_float2(b.x, b.y));
    h[3] = __float22half2_rn(make_float2(b.z, b.w));
    ((float4*)out)[i] = *(const float4*)h;
}

// ---------------- histogram of row indices ----------------
__global__ __launch_bounds__(256) void hist_kernel(const int* __restrict__ row,
                                                   int* __restrict__ hist, int e) {
    int i = blockIdx.x * blockDim.x + threadIdx.x;
    if (i < e) atomicAdd(&hist[row[i]], 1);
}

// ---------------- phase A: per-block partial sums ----------------
__global__ __launch_bounds__(256) void partial_kernel(const int* __restrict__ hist,
                                                      int* __restrict__ bsum, int n) {
    int i = blockIdx.x * 256 + threadIdx.x;
    int v = (i < n) ? hist[i] : 0;
#pragma unroll
    for (int off = 1; off < 64; off <<= 1) v += __shfl_xor(v, off);
    __shared__ int ws[4];
    int lane = threadIdx.x & 63, w = threadIdx.x >> 6;
    if (lane == 0) ws[w] = v;
    __syncthreads();
    if (threadIdx.x == 0) bsum[blockIdx.x] = ws[0] + ws[1] + ws[2] + ws[3];
}

// ---------------- phase B+C fused: block-prefix of bsum + per-block scan ----------------
__global__ __launch_bounds__(256) void finalize_kernel(const int* __restrict__ hist,
                                                       const int* __restrict__ bsum,
                                                       int* __restrict__ offsets,
                                                       int* __restrict__ cursor,
                                                       float* __restrict__ rdeg, int n) {
    __shared__ int wt[4];
    int t = threadIdx.x, lane = t & 63, w = t >> 6;

    int p = 0;
    for (int k = t; k < blockIdx.x; k += 256) p += bsum[k];
#pragma unroll
    for (int off = 1; off < 64; off <<= 1) p += __shfl_xor(p, off);
    if (lane == 0) wt[w] = p;
    __syncthreads();
    int blockbase = wt[0] + wt[1] + wt[2] + wt[3];
    __syncthreads();

    int i = blockIdx.x * 256 + t;
    int v = (i < n) ? hist[i] : 0;
    int iv = v;
#pragma unroll
    for (int off = 1; off < 64; off <<= 1) {
        int n2 = __shfl_up(iv, off);
        if (lane >= off) iv += n2;
    }
    if (lane == 63) wt[w] = iv;
    __syncthreads();
    int add = blockbase;
    for (int k = 0; k < w; ++k) add += wt[k];
    int excl = iv - v + add;
    if (i < n) {
        offsets[i] = excl;
        cursor[i]  = excl;
        rdeg[i]    = 1.0f / fmaxf((float)v, 1.0f);
    }
}

// ---------------- fill CSR col list via atomic cursors ----------------
__global__ __launch_bounds__(256) void fill_kernel(const int* __restrict__ ei, int e,
                                                   int* __restrict__ cursor,
                                                   int* __restrict__ csr) {
    int i = blockIdx.x * blockDim.x + threadIdx.x;
    if (i < e) {
        int r = ei[i];
        int c = ei[e + i];
        int pos = atomicAdd(&cursor[r], 1);
        csr[pos] = c;
    }
}

// ---------------- MFMA linear: z[r][j] = sum_k src[r][k] * W[j][k]  (fp16 in/out) ----------------
// Block = 256 thr = 4 waves; block tile 64 rows; wave tile 16 rows x 128 cols.
// A-frag: lane l holds src[row0+(l&15)][kk*32+(l>>4)*8 + j]  (one 16B load per kk).
// B-frag: from LDS-staged WB (fragment-ready), stride-16B ds_read_b128 (conflict-free).
// D: lane l reg r -> z[row0+(l>>4)*4+r][c*16+(l&15)].
__global__ __launch_bounds__(256) void linear_kernel(const __half* __restrict__ src,
                                                     const __half* __restrict__ WB,
                                                     __half* __restrict__ z, int n) {
    alignas(16) __shared__ __half Bs[D * D];
    // stage WB -> LDS: 2048 float4s
    {
        const float4* wb4 = (const float4*)WB;
        float4* bs4 = (float4*)Bs;
        for (int i = threadIdx.x; i < D * D / 8; i += 256) bs4[i] = wb4[i];
    }
    __syncthreads();

    int l    = threadIdx.x & 63;
    int wv   = threadIdx.x >> 6;
    int row0 = blockIdx.x * TILE_R + wv * 16;
    int arow = row0 + (l & 15);
    bool rowok = arow < n;

    h8 a[4];
#pragma unroll
    for (int kk = 0; kk < 4; ++kk) {
        if (rowok)
            a[kk] = *(const h8*)&src[(size_t)arow * D + kk * 32 + (l >> 4) * 8];
        else
            a[kk] = (h8)(_Float16)0.0f;
    }

    int srow = row0 + (l >> 4) * 4;   // store row base (4 consecutive regs)
#pragma unroll
    for (int c = 0; c < 8; ++c) {
        f4 acc = {0.f, 0.f, 0.f, 0.f};
#pragma unroll
        for (int kk = 0; kk < 4; ++kk) {
            h8 b = *(const h8*)&Bs[(((c * 4 + kk) * 64) + l) * 8];
            acc = __builtin_amdgcn_mfma_f32_16x16x32_f16(a[kk], b, acc, 0, 0, 0);
        }
        int col = c * 16 + (l & 15);
#pragma unroll
        for (int r = 0; r < 4; ++r) {
            int ro = srow + r;
            if (ro < n) z[(size_t)ro * D + col] = __float2half(acc[r]);
        }
    }
}

// ---------------- gather z rows, mean-normalize, +bias, relu -> round output ----------------
// 4 nodes per wave: 16-lane group per node, each lane loads float4 (8 halves) of the 256B row.
__device__ inline void addh8(float* a, float4 v) {
    const __half2* h = (const __half2*)&v;
    float2 f0 = __half22float2(h[0]);
    float2 f1 = __half22float2(h[1]);
    float2 f2 = __half22float2(h[2]);
    float2 f3 = __half22float2(h[3]);
    a[0] += f0.x; a[1] += f0.y; a[2] += f1.x; a[3] += f1.y;
    a[4] += f2.x; a[5] += f2.y; a[6] += f3.x; a[7] += f3.y;
}

template <int OUT_HALF>
__global__ __launch_bounds__(256) void gather_kernel(const __half* __restrict__ z,
                                                     const int* __restrict__ offsets,
                                                     const int* __restrict__ hist,
                                                     const int* __restrict__ csr,
                                                     const float* __restrict__ rdeg,
                                                     const float* __restrict__ bias,
                                                     void* __restrict__ outv, int n) {
    int tid  = blockIdx.x * 256 + threadIdx.x;
    int wave = tid >> 6;
    int lane = threadIdx.x & 63;
    int g    = lane >> 4;
    int gl   = lane & 15;
    int node = wave * 4 + g;
    if (node >= n) return;

    int start = offsets[node];
    int cnt   = hist[node];
    const float4* base = (const float4*)z;

    float acc[8] = {0.f, 0.f, 0.f, 0.f, 0.f, 0.f, 0.f, 0.f};
    int i = 0;
    for (; i + 8 <= cnt; i += 8) {
        int c0 = csr[start + i];
        int c1 = csr[start + i + 1];
        int c2 = csr[start + i + 2];
        int c3 = csr[start + i + 3];
        int c4 = csr[start + i + 4];
        int c5 = csr[start + i + 5];
        int c6 = csr[start + i + 6];
        int c7 = csr[start + i + 7];
        float4 v0 = base[(size_t)c0 * 16 + gl];
        float4 v1 = base[(size_t)c1 * 16 + gl];
        float4 v2 = base[(size_t)c2 * 16 + gl];
        float4 v3 = base[(size_t)c3 * 16 + gl];
        float4 v4 = base[(size_t)c4 * 16 + gl];
        float4 v5 = base[(size_t)c5 * 16 + gl];
        float4 v6 = base[(size_t)c6 * 16 + gl];
        float4 v7 = base[(size_t)c7 * 16 + gl];
        addh8(acc, v0); addh8(acc, v1); addh8(acc, v2); addh8(acc, v3);
        addh8(acc, v4); addh8(acc, v5); addh8(acc, v6); addh8(acc, v7);
    }
    if (i + 4 <= cnt) {
        int c0 = csr[start + i];
        int c1 = csr[start + i + 1];
        int c2 = csr[start + i + 2];
        int c3 = csr[start + i + 3];
        float4 v0 = base[(size_t)c0 * 16 + gl];
        float4 v1 = base[(size_t)c1 * 16 + gl];
        float4 v2 = base[(size_t)c2 * 16 + gl];
        float4 v3 = base[(size_t)c3 * 16 + gl];
        addh8(acc, v0); addh8(acc, v1); addh8(acc, v2); addh8(acc, v3);
        i += 4;
    }
    int rem = cnt - i;
    if (rem > 0) {
        int c0 = csr[start + i];
        int c1 = csr[start + min(i + 1, cnt - 1)];
        int c2 = csr[start + min(i + 2, cnt - 1)];
        float4 v0 = base[(size_t)c0 * 16 + gl];
        float4 v1 = base[(size_t)c1 * 16 + gl];
        float4 v2 = base[(size_t)c2 * 16 + gl];
        addh8(acc, v0);
        if (rem > 1) addh8(acc, v1);
        if (rem > 2) addh8(acc, v2);
    }

    float rd = rdeg[node];
    float4 b0 = ((const float4*)bias)[gl * 2];
    float4 b1 = ((const float4*)bias)[gl * 2 + 1];
    float o[8];
    o[0] = fmaxf(acc[0] * rd + b0.x, 0.f);
    o[1] = fmaxf(acc[1] * rd + b0.y, 0.f);
    o[2] = fmaxf(acc[2] * rd + b0.z, 0.f);
    o[3] = fmaxf(acc[3] * rd + b0.w, 0.f);
    o[4] = fmaxf(acc[4] * rd + b1.x, 0.f);
    o[5] = fmaxf(acc[5] * rd + b1.y, 0.f);
    o[6] = fmaxf(acc[6] * rd + b1.z, 0.f);
    o[7] = fmaxf(acc[7] * rd + b1.w, 0.f);

    if (OUT_HALF) {
        __half2 h[4];
        h[0] = __float22half2_rn(make_float2(o[0], o[1]));
        h[1] = __float22half2_rn(make_float2(o[2], o[3]));
        h[2] = __float22half2_rn(make_float2(o[4], o[5]));
        h[3] = __float22half2_rn(make_float2(o[6], o[7]));
        ((float4*)outv)[(size_t)node * 16 + gl] = *(const float4*)h;
    } else {
        float4* o4 = (float4*)outv;
        o4[(size_t)node * 32 + gl * 2]     = make_float4(o[0], o[1], o[2], o[3]);
        o4[(size_t)node * 32 + gl * 2 + 1] = make_float4(o[4], o[5], o[6], o[7]);
    }
}

extern "C" void kernel_launch(void* const* d_in, const int* in_sizes, int n_in,
                              void* d_out, int out_size, void* d_ws, size_t ws_size,
                              hipStream_t stream) {
    const float* x  = (const float*)d_in[0];
    const int*   ei = (const int*)d_in[1];
    const float* W1 = (const float*)d_in[2];
    const float* b1 = (const float*)d_in[3];
    const float* W2 = (const float*)d_in[4];
    const float* b2 = (const float*)d_in[5];
    float* out = (float*)d_out;

    int N = in_sizes[0] / D;   // 50000
    int E = in_sizes[1] / 2;   // 600000
    int NB = (N + 255) / 256;  // 196 scan blocks

    // workspace carve (all offsets stay 16B-aligned)
    int* hist    = (int*)d_ws;
    int* offsets = hist + N;
    int* cursor  = offsets + N;
    int* csr     = cursor + N;
    float* rdeg  = (float*)(csr + E);
    int* bsum    = (int*)(rdeg + N);
    __half* WB1  = (__half*)(bsum + ((NB + 3) & ~3));  // fragment-ready W1 (fp16, 32KB)
    __half* WB2  = WB1 + D * D;
    __half* xh   = WB2 + D * D;              // x in fp16 [N][D]
    __half* hh   = xh + (size_t)N * D;       // round-1 output h in fp16 [N][D]
    __half* zz   = hh + (size_t)N * D;       // per-round z = src @ W^T in fp16 [N][D]

    prep_kernel<<<(N * D / 8 + 255) / 256 + 2, 256, 0, stream>>>(x, xh, N * D / 8, hist, N,
                                                                 W1, WB1, W2, WB2);
    hist_kernel<<<(E + 255) / 256, 256, 0, stream>>>(ei, hist, E);
    partial_kernel<<<NB, 256, 0, stream>>>(hist, bsum, N);
    finalize_kernel<<<NB, 256, 0, stream>>>(hist, bsum, offsets, cursor, rdeg, N);
    fill_kernel<<<(E + 255) / 256, 256, 0, stream>>>(ei, E, cursor, csr);

    int nblk = (N + TILE_R - 1) / TILE_R;
    int gblk = ((N + 3) / 4 * 64 + 255) / 256;   // 4 nodes per wave
    // round 1: z1 = xh @ W1^T ; h = relu(S z1 + b1) -> hh (fp16)
    linear_kernel<<<nblk, 256, 0, stream>>>(xh, WB1, zz, N);
    gather_kernel<1><<<gblk, 256, 0, stream>>>(zz, offsets, hist, csr, rdeg, b1, hh, N);
    // round 2: z2 = hh @ W2^T ; out = relu(S z2 + b2) -> f32 out
    linear_kernel<<<nblk, 256, 0, stream>>>(hh, WB2, zz, N);
    gather_kernel<0><<<gblk, 256, 0, stream>>>(zz, offsets, hist, csr, rdeg, b2, out, N);
}